// Round 1
// 1617.894 us; speedup vs baseline: 1.7090x; 1.7090x over previous
//
#include <hip/hip_runtime.h>
#include <hip/hip_fp16.h>

// Bidirectional GRU: T=512, B=512, I=100, H=96, gate order (r,z,n).
// proj_mfma_kernel: xp[dir][m][g] = x_row . W_ih[g] + b_ih[g] via f16 MFMA,
//                   fp16 output in d_ws; dir=1 stored time-reversed.
// scan_kernel: unchanged from previous round (next optimization target).

#define TT 512
#define BB 512
#define II 100
#define HH 96
#define GG 288   // 3*H
#define NB 4     // batch rows per scan block

typedef _Float16 half8 __attribute__((ext_vector_type(8)));
typedef float floatx4 __attribute__((ext_vector_type(4)));

__device__ __forceinline__ float fast_rcp(float x) { return __builtin_amdgcn_rcpf(x); }
__device__ __forceinline__ float sigmoidf_(float x) { return fast_rcp(1.f + __expf(-x)); }
__device__ __forceinline__ float tanhf_(float x) {
    float e = __expf(-2.f * x);
    return (1.f - e) * fast_rcp(1.f + e);
}

// ---------------- input projection (MFMA) ----------------
// grid: (TT, 2) — block bx handles the 512 rows of time-step t=bx for dir=by.
// block: 192 threads = 3 waves; wave w owns gates [w*96, w*96+96).
// B (W_ih^T) fragments held in VGPRs for the whole kernel; K=100 padded to 128.
__global__ __launch_bounds__(192) void proj_mfma_kernel(
    const float* __restrict__ x,
    const float* __restrict__ wih_f, const float* __restrict__ bih_f,
    const float* __restrict__ wih_b, const float* __restrict__ bih_b,
    __half* __restrict__ xp)
{
    const int dir = blockIdx.y;
    const int t   = blockIdx.x;
    const int tid = threadIdx.x;
    const int w   = tid >> 6;      // wave 0..2
    const int l   = tid & 63;
    const int l15 = l & 15;
    const int kg  = l >> 4;        // 0..3 (k-group)
    const int n0  = w * 96;

    const float* w_ih = dir ? wih_b : wih_f;
    const float* b_ih = dir ? bih_b : bih_f;

    // ---- B fragments: Bf[nt][kc]; lane holds W[g][kb..kb+7], g = n0+nt*16+(l&15),
    // kb = kc*32 + kg*8. k >= 100 zero-padded.
    half8 Bf[6][4];
    float bias[6];
#pragma unroll
    for (int nt = 0; nt < 6; ++nt) {
        const int g = n0 + nt * 16 + l15;
        bias[nt] = b_ih[g];
        const float* wr = w_ih + (size_t)g * II;
#pragma unroll
        for (int kc = 0; kc < 4; ++kc) {
            half8 f;
#pragma unroll
            for (int j = 0; j < 8; ++j) f[j] = (_Float16)0.f;
            if (kc < 3) {
                const int kb = kc * 32 + kg * 8;   // <= 88, +7 = 95 < 100: all valid
                const float4* p = (const float4*)(wr + kb);
                float4 a = p[0], b = p[1];
                f[0] = (_Float16)a.x; f[1] = (_Float16)a.y;
                f[2] = (_Float16)a.z; f[3] = (_Float16)a.w;
                f[4] = (_Float16)b.x; f[5] = (_Float16)b.y;
                f[6] = (_Float16)b.z; f[7] = (_Float16)b.w;
            } else if (kg == 0) {
                const float4* p = (const float4*)(wr + 96);  // k = 96..99 valid
                float4 a = p[0];
                f[0] = (_Float16)a.x; f[1] = (_Float16)a.y;
                f[2] = (_Float16)a.z; f[3] = (_Float16)a.w;
            }
            Bf[nt][kc] = f;
        }
    }

    // ---- LDS A tile: 32 rows x 136 f16 (272B stride -> ~2-way banks, 16B aligned)
    __shared__ __half xs[32][136];
    // zero the k in [100,128) pad once (never overwritten by staging)
    for (int i = tid; i < 32 * 28; i += 192) {
        const int row = i / 28, c = i - row * 28;
        xs[row][100 + c] = __float2half(0.f);
    }

    __half* out = xp + (size_t)dir * (size_t)(TT * BB) * GG;
    const size_t orow_base = dir ? (size_t)(TT - 1 - t) * BB : (size_t)t * BB;

    for (int s = 0; s < 16; ++s) {
        const int r0 = s * 32;                    // batch rows r0..r0+31
        __syncthreads();                          // prev strip's ds_reads done
        // stage 32 rows of x -> f16 LDS (coalesced float2 reads)
        const float2* src = (const float2*)(x + ((size_t)t * BB + r0) * II);
        for (int i = tid; i < 1600; i += 192) {
            float2 v = src[i];
            const int row = i / 50, c2 = i - row * 50;
            *(__half2*)&xs[row][2 * c2] = __floats2half2_rn(v.x, v.y);
        }
        __syncthreads();

        floatx4 acc[2][6];
#pragma unroll
        for (int mt = 0; mt < 2; ++mt)
#pragma unroll
            for (int nt = 0; nt < 6; ++nt) {
                acc[mt][nt][0] = bias[nt]; acc[mt][nt][1] = bias[nt];
                acc[mt][nt][2] = bias[nt]; acc[mt][nt][3] = bias[nt];
            }

#pragma unroll
        for (int mt = 0; mt < 2; ++mt) {
            // A fragments: row = mt*16 + (l&15), k = kc*32 + kg*8 + j
            half8 Af[4];
            const char* abase = (const char*)&xs[0][0] + (mt * 16 + l15) * 272 + kg * 16;
#pragma unroll
            for (int kc = 0; kc < 4; ++kc)
                Af[kc] = *(const half8*)(abase + kc * 64);
#pragma unroll
            for (int nt = 0; nt < 6; ++nt)
#pragma unroll
                for (int kc = 0; kc < 4; ++kc)
                    acc[mt][nt] = __builtin_amdgcn_mfma_f32_16x16x32_f16(
                        Af[kc], Bf[nt][kc], acc[mt][nt], 0, 0, 0);
        }

        // store: C row = kg*4 + i (local), col = l&15
#pragma unroll
        for (int mt = 0; mt < 2; ++mt) {
#pragma unroll
            for (int nt = 0; nt < 6; ++nt) {
                const int g = n0 + nt * 16 + l15;
#pragma unroll
                for (int i = 0; i < 4; ++i) {
                    const int b = r0 + mt * 16 + kg * 4 + i;
                    out[(orow_base + b) * GG + g] = __float2half(acc[mt][nt][i]);
                }
            }
        }
    }
}

// ---------------- recurrent scan (unchanged) ----------------
// grid: (B/NB, 2), block: 288. Thread g owns gate output g for NB rows;
// W_hh[g][0..95] in regs; h state in LDS (broadcast float4 reads).
__global__ __launch_bounds__(288) void scan_kernel(
    const __half* __restrict__ xp,
    const float* __restrict__ whh_f, const float* __restrict__ bhh_f,
    const float* __restrict__ whh_b, const float* __restrict__ bhh_b,
    float* __restrict__ out)
{
    const int dir = blockIdx.y;
    const int g = threadIdx.x;
    const int b0 = blockIdx.x * NB;
    const float* w_hh = dir ? whh_b : whh_f;
    const float* b_hh = dir ? bhh_b : bhh_f;

    float w[HH];
#pragma unroll
    for (int k = 0; k < HH; ++k) w[k] = w_hh[g * HH + k];
    const float bias = b_hh[g];

    __shared__ float h[NB][HH];
    __shared__ float rb[NB][HH];
    __shared__ float zb[NB][HH];

    for (int i = threadIdx.x; i < NB * HH; i += 288) ((float*)h)[i] = 0.f;
    __syncthreads();

    const __half* xpd = xp + (size_t)dir * (size_t)(TT * BB) * GG;
    const int cls = g / HH;   // 0=r, 1=z, 2=n
    const int j = g - cls * HH;

    // prefetch xp for t=0
    __half xpc[NB], xpn[NB];
#pragma unroll
    for (int b = 0; b < NB; ++b)
        xpc[b] = xpd[((size_t)0 * BB + b0 + b) * GG + g];

    for (int t = 0; t < TT; ++t) {
        // issue next step's xp loads early (hide HBM latency under the dot)
        if (t + 1 < TT) {
            const size_t nrow = ((size_t)(t + 1) * BB + b0) * GG;
#pragma unroll
            for (int b = 0; b < NB; ++b) xpn[b] = xpd[nrow + (size_t)b * GG + g];
        }

        float hp[NB];
#pragma unroll
        for (int b = 0; b < NB; ++b) {
            float acc = bias;
            const float4* hr = (const float4*)h[b];
#pragma unroll
            for (int k4 = 0; k4 < HH / 4; ++k4) {
                float4 hv = hr[k4];  // broadcast
                acc += hv.x * w[4 * k4 + 0];
                acc += hv.y * w[4 * k4 + 1];
                acc += hv.z * w[4 * k4 + 2];
                acc += hv.w * w[4 * k4 + 3];
            }
            hp[b] = acc;
        }

        if (cls == 0) {
#pragma unroll
            for (int b = 0; b < NB; ++b)
                rb[b][j] = sigmoidf_(__half2float(xpc[b]) + hp[b]);
        } else if (cls == 1) {
#pragma unroll
            for (int b = 0; b < NB; ++b)
                zb[b][j] = sigmoidf_(__half2float(xpc[b]) + hp[b]);
        }
        __syncthreads();  // r,z visible; all h reads of this step done

        if (cls == 2) {
            const int orow = (dir == 0) ? t : (TT - 1 - t);
#pragma unroll
            for (int b = 0; b < NB; ++b) {
                const float r = rb[b][j];
                const float z = zb[b][j];
                const float n = tanhf_(__half2float(xpc[b]) + r * hp[b]);
                const float hn = (1.f - z) * n + z * h[b][j];
                h[b][j] = hn;
                out[((size_t)orow * BB + (b0 + b)) * (2 * HH) + dir * HH + j] = hn;
            }
        }
        __syncthreads();  // h update visible before next step

#pragma unroll
        for (int b = 0; b < NB; ++b) xpc[b] = xpn[b];
    }
}

__global__ void sentinel_kernel(float* out) {
    if (threadIdx.x == 0 && blockIdx.x == 0) out[0] = 1e9f;  // ws too small marker
}

extern "C" void kernel_launch(void* const* d_in, const int* in_sizes, int n_in,
                              void* d_out, int out_size, void* d_ws, size_t ws_size,
                              hipStream_t stream)
{
    const float* x     = (const float*)d_in[0];
    const float* wih_f = (const float*)d_in[1];
    const float* whh_f = (const float*)d_in[2];
    const float* bih_f = (const float*)d_in[3];
    const float* bhh_f = (const float*)d_in[4];
    const float* wih_b = (const float*)d_in[5];
    const float* whh_b = (const float*)d_in[6];
    const float* bih_b = (const float*)d_in[7];
    const float* bhh_b = (const float*)d_in[8];
    float* out = (float*)d_out;

    const size_t ws_needed = (size_t)2 * TT * BB * GG * sizeof(__half);  // ~302 MB
    if (ws_size < ws_needed) {
        sentinel_kernel<<<1, 64, 0, stream>>>(out);
        return;
    }
    __half* xp = (__half*)d_ws;

    dim3 pgrid(TT, 2);
    proj_mfma_kernel<<<pgrid, 192, 0, stream>>>(x, wih_f, bih_f, wih_b, bih_b, xp);

    dim3 sgrid(BB / NB, 2);
    scan_kernel<<<sgrid, 288, 0, stream>>>(xp, whh_f, bhh_f, whh_b, bhh_b, out);
}

// Round 2
// 1118.391 us; speedup vs baseline: 2.4723x; 1.4466x over previous
//
#include <hip/hip_runtime.h>
#include <hip/hip_fp16.h>

// Bidirectional GRU: T=512, B=512, I=100, H=96, gate order (r,z,n).
// proj_mfma_kernel: xp[dir][m][g] = x_row . W_ih[g] + b_ih[g] via f16 MFMA (unchanged).
// scan_mfma_kernel: recurrent matmul via MFMA, swapped operands:
//   D[gate][row] = W_hh . h^T; A=W_hh (persistent VGPR, f16 hi+lo split),
//   B=h (f16 hi+lo in LDS, double-buffered). r/z/n for one (row,j) are
//   colocated in one lane -> gate math lane-local, h_old in registers.

#define TT 512
#define BB 512
#define II 100
#define HH 96
#define GG 288   // 3*H
#define SH 104   // LDS h row stride in halves (208B: spreads b128 over 8 bank-groups)

typedef _Float16 half8 __attribute__((ext_vector_type(8)));
typedef _Float16 half4 __attribute__((ext_vector_type(4)));
typedef float floatx4 __attribute__((ext_vector_type(4)));

__device__ __forceinline__ float fast_rcp(float x) { return __builtin_amdgcn_rcpf(x); }
__device__ __forceinline__ float sigmoidf_(float x) { return fast_rcp(1.f + __expf(-x)); }
__device__ __forceinline__ float tanhf_(float x) {
    float e = __expf(-2.f * x);
    return (1.f - e) * fast_rcp(1.f + e);
}

// ---------------- input projection (MFMA) ----------------
// grid: (TT, 2) — block bx handles the 512 rows of time-step t=bx for dir=by.
// block: 192 threads = 3 waves; wave w owns gates [w*96, w*96+96).
__global__ __launch_bounds__(192) void proj_mfma_kernel(
    const float* __restrict__ x,
    const float* __restrict__ wih_f, const float* __restrict__ bih_f,
    const float* __restrict__ wih_b, const float* __restrict__ bih_b,
    __half* __restrict__ xp)
{
    const int dir = blockIdx.y;
    const int t   = blockIdx.x;
    const int tid = threadIdx.x;
    const int w   = tid >> 6;      // wave 0..2
    const int l   = tid & 63;
    const int l15 = l & 15;
    const int kg  = l >> 4;        // 0..3 (k-group)
    const int n0  = w * 96;

    const float* w_ih = dir ? wih_b : wih_f;
    const float* b_ih = dir ? bih_b : bih_f;

    half8 Bf[6][4];
    float bias[6];
#pragma unroll
    for (int nt = 0; nt < 6; ++nt) {
        const int g = n0 + nt * 16 + l15;
        bias[nt] = b_ih[g];
        const float* wr = w_ih + (size_t)g * II;
#pragma unroll
        for (int kc = 0; kc < 4; ++kc) {
            half8 f;
#pragma unroll
            for (int j = 0; j < 8; ++j) f[j] = (_Float16)0.f;
            if (kc < 3) {
                const int kb = kc * 32 + kg * 8;   // <= 88, +7 = 95 < 100: valid
                const float4* p = (const float4*)(wr + kb);
                float4 a = p[0], b = p[1];
                f[0] = (_Float16)a.x; f[1] = (_Float16)a.y;
                f[2] = (_Float16)a.z; f[3] = (_Float16)a.w;
                f[4] = (_Float16)b.x; f[5] = (_Float16)b.y;
                f[6] = (_Float16)b.z; f[7] = (_Float16)b.w;
            } else if (kg == 0) {
                const float4* p = (const float4*)(wr + 96);  // k = 96..99
                float4 a = p[0];
                f[0] = (_Float16)a.x; f[1] = (_Float16)a.y;
                f[2] = (_Float16)a.z; f[3] = (_Float16)a.w;
            }
            Bf[nt][kc] = f;
        }
    }

    __shared__ __half xs[32][136];
    for (int i = tid; i < 32 * 28; i += 192) {
        const int row = i / 28, c = i - row * 28;
        xs[row][100 + c] = __float2half(0.f);
    }

    __half* out = xp + (size_t)dir * (size_t)(TT * BB) * GG;
    const size_t orow_base = dir ? (size_t)(TT - 1 - t) * BB : (size_t)t * BB;

    for (int s = 0; s < 16; ++s) {
        const int r0 = s * 32;
        __syncthreads();
        const float2* src = (const float2*)(x + ((size_t)t * BB + r0) * II);
        for (int i = tid; i < 1600; i += 192) {
            float2 v = src[i];
            const int row = i / 50, c2 = i - row * 50;
            *(__half2*)&xs[row][2 * c2] = __floats2half2_rn(v.x, v.y);
        }
        __syncthreads();

        floatx4 acc[2][6];
#pragma unroll
        for (int mt = 0; mt < 2; ++mt)
#pragma unroll
            for (int nt = 0; nt < 6; ++nt) {
                acc[mt][nt][0] = bias[nt]; acc[mt][nt][1] = bias[nt];
                acc[mt][nt][2] = bias[nt]; acc[mt][nt][3] = bias[nt];
            }

#pragma unroll
        for (int mt = 0; mt < 2; ++mt) {
            half8 Af[4];
            const char* abase = (const char*)&xs[0][0] + (mt * 16 + l15) * 272 + kg * 16;
#pragma unroll
            for (int kc = 0; kc < 4; ++kc)
                Af[kc] = *(const half8*)(abase + kc * 64);
#pragma unroll
            for (int nt = 0; nt < 6; ++nt)
#pragma unroll
                for (int kc = 0; kc < 4; ++kc)
                    acc[mt][nt] = __builtin_amdgcn_mfma_f32_16x16x32_f16(
                        Af[kc], Bf[nt][kc], acc[mt][nt], 0, 0, 0);
        }

#pragma unroll
        for (int mt = 0; mt < 2; ++mt) {
#pragma unroll
            for (int nt = 0; nt < 6; ++nt) {
                const int g = n0 + nt * 16 + l15;
#pragma unroll
                for (int i = 0; i < 4; ++i) {
                    const int b = r0 + mt * 16 + kg * 4 + i;
                    out[(orow_base + b) * GG + g] = __float2half(acc[mt][nt][i]);
                }
            }
        }
    }
}

// ---------------- recurrent scan (MFMA) ----------------
// grid: (BB/16, 2), block: 192 = 3 waves. Block owns 16 batch rows (r0..r0+15).
// Wave w owns hidden cols j in [32w, 32w+32): M-tiles {2w,2w+1} per class.
// Lane (l15,kg): C element = (gate_local kg*4+i, row l15). r/z/n colocated.
__global__ __launch_bounds__(192, 1) void scan_mfma_kernel(
    const __half* __restrict__ xp,
    const float* __restrict__ whh_f, const float* __restrict__ bhh_f,
    const float* __restrict__ whh_b, const float* __restrict__ bhh_b,
    float* __restrict__ out)
{
    const int dir = blockIdx.y;
    const int r0  = blockIdx.x * 16;
    const int tid = threadIdx.x;
    const int w   = tid >> 6;
    const int l   = tid & 63;
    const int l15 = l & 15;
    const int kg  = l >> 4;

    const float* whh = dir ? whh_b : whh_f;
    const float* bhh = dir ? bhh_b : bhh_f;

    // A-fragments (W_hh), split f16: tile tl = cls*2+tg, gate = cls*96+(2w+tg)*16+l15
    half8 Whi[6][3], Wlo[6][3];
    floatx4 bias[6];
#pragma unroll
    for (int cls = 0; cls < 3; ++cls)
#pragma unroll
        for (int tg = 0; tg < 2; ++tg) {
            const int tl = cls * 2 + tg;
            const int g  = cls * 96 + (2 * w + tg) * 16 + l15;
            const float* wr = whh + (size_t)g * HH;
#pragma unroll
            for (int kc = 0; kc < 3; ++kc) {
                const float4* p = (const float4*)(wr + kc * 32 + kg * 8);
                float4 a = p[0], b = p[1];
                half8 hi, lo;
                float v[8] = {a.x, a.y, a.z, a.w, b.x, b.y, b.z, b.w};
#pragma unroll
                for (int j = 0; j < 8; ++j) {
                    _Float16 h = (_Float16)v[j];
                    hi[j] = h;
                    lo[j] = (_Float16)(v[j] - (float)h);
                }
                Whi[tl][kc] = hi;
                Wlo[tl][kc] = lo;
            }
            const int gb = cls * 96 + (2 * w + tg) * 16 + kg * 4;
            bias[tl][0] = bhh[gb + 0]; bias[tl][1] = bhh[gb + 1];
            bias[tl][2] = bhh[gb + 2]; bias[tl][3] = bhh[gb + 3];
        }

    // h state: f16 hi/lo, double-buffered, padded stride
    __shared__ __align__(16) _Float16 hHi[2][16][SH];
    __shared__ __align__(16) _Float16 hLo[2][16][SH];
    for (int i = tid; i < 2 * 16 * SH / 2; i += 192) {
        ((unsigned*)hHi)[i] = 0u;
        ((unsigned*)hLo)[i] = 0u;
    }

    float hold[8];  // h_old[row=l15][j = 32w+16tg+4kg+i], exact fp32
#pragma unroll
    for (int i = 0; i < 8; ++i) hold[i] = 0.f;

    const __half* xpd  = xp + (size_t)dir * (size_t)(TT * BB) * GG;
    const __half* xptr = xpd + ((size_t)(r0 + l15)) * GG + 32 * w + 4 * kg;
    const size_t  xstep = (size_t)BB * GG;  // halves per time step

    // current xp (t=0): run (cls,tg) at byte offset (cls*96+16*tg)*2 <= 416 (imm-foldable)
    half4 xc[6], xn[6];
#pragma unroll
    for (int cls = 0; cls < 3; ++cls)
#pragma unroll
        for (int tg = 0; tg < 2; ++tg)
            xc[cls * 2 + tg] = *(const half4*)(xptr + cls * 96 + tg * 16);
    const __half* xq = xptr + xstep;  // prefetch pointer (t+1)

    __syncthreads();

    for (int t = 0; t < TT; ++t) {
        // prefetch next step's xp early (hidden under MFMA+gates)
        if (t + 1 < TT) {
#pragma unroll
            for (int cls = 0; cls < 3; ++cls)
#pragma unroll
                for (int tg = 0; tg < 2; ++tg)
                    xn[cls * 2 + tg] = *(const half4*)(xq + cls * 96 + tg * 16);
        }

        const int cur = t & 1, nxt = cur ^ 1;

        // B-fragments: h^T, lane col=l15(=row), k = kc*32+kg*8+j
        half8 hb[3], lb[3];
#pragma unroll
        for (int kc = 0; kc < 3; ++kc) {
            hb[kc] = *(const half8*)&hHi[cur][l15][kc * 32 + kg * 8];
            lb[kc] = *(const half8*)&hLo[cur][l15][kc * 32 + kg * 8];
        }

        floatx4 acc[6];
#pragma unroll
        for (int tl = 0; tl < 6; ++tl) {
            acc[tl] = bias[tl];
#pragma unroll
            for (int kc = 0; kc < 3; ++kc) {
                acc[tl] = __builtin_amdgcn_mfma_f32_16x16x32_f16(Whi[tl][kc], hb[kc], acc[tl], 0, 0, 0);
                acc[tl] = __builtin_amdgcn_mfma_f32_16x16x32_f16(Whi[tl][kc], lb[kc], acc[tl], 0, 0, 0);
                acc[tl] = __builtin_amdgcn_mfma_f32_16x16x32_f16(Wlo[tl][kc], hb[kc], acc[tl], 0, 0, 0);
            }
        }

        const int orow = dir ? (TT - 1 - t) : t;
        float* obase = out + ((size_t)orow * BB + r0 + l15) * (2 * HH) + dir * HH + 32 * w + 4 * kg;

#pragma unroll
        for (int tg = 0; tg < 2; ++tg) {
            floatx4 ar = acc[tg], az = acc[2 + tg], an = acc[4 + tg];
            half4 xr = xc[tg], xz = xc[2 + tg], xv = xc[4 + tg];
            float4 o;
            half4 nhi, nlo;
#pragma unroll
            for (int i = 0; i < 4; ++i) {
                const float r = sigmoidf_((float)xr[i] + ar[i]);
                const float z = sigmoidf_((float)xz[i] + az[i]);
                const float n = tanhf_((float)xv[i] + r * an[i]);
                const float hv = z * (hold[tg * 4 + i] - n) + n;
                hold[tg * 4 + i] = hv;
                ((float*)&o)[i] = hv;
                const _Float16 hh = (_Float16)hv;
                nhi[i] = hh;
                nlo[i] = (_Float16)(hv - (float)hh);
            }
            *(float4*)(obase + tg * 16) = o;
            *(half4*)&hHi[nxt][l15][32 * w + 16 * tg + 4 * kg] = nhi;
            *(half4*)&hLo[nxt][l15][32 * w + 16 * tg + 4 * kg] = nlo;
        }

        __syncthreads();  // h[nxt] complete before next step reads it
        xq += xstep;
#pragma unroll
        for (int i = 0; i < 6; ++i) xc[i] = xn[i];
    }
}

__global__ void sentinel_kernel(float* out) {
    if (threadIdx.x == 0 && blockIdx.x == 0) out[0] = 1e9f;  // ws too small marker
}

extern "C" void kernel_launch(void* const* d_in, const int* in_sizes, int n_in,
                              void* d_out, int out_size, void* d_ws, size_t ws_size,
                              hipStream_t stream)
{
    const float* x     = (const float*)d_in[0];
    const float* wih_f = (const float*)d_in[1];
    const float* whh_f = (const float*)d_in[2];
    const float* bih_f = (const float*)d_in[3];
    const float* bhh_f = (const float*)d_in[4];
    const float* wih_b = (const float*)d_in[5];
    const float* whh_b = (const float*)d_in[6];
    const float* bih_b = (const float*)d_in[7];
    const float* bhh_b = (const float*)d_in[8];
    float* out = (float*)d_out;

    const size_t ws_needed = (size_t)2 * TT * BB * GG * sizeof(__half);  // ~302 MB
    if (ws_size < ws_needed) {
        sentinel_kernel<<<1, 64, 0, stream>>>(out);
        return;
    }
    __half* xp = (__half*)d_ws;

    dim3 pgrid(TT, 2);
    proj_mfma_kernel<<<pgrid, 192, 0, stream>>>(x, wih_f, bih_f, wih_b, bih_b, xp);

    dim3 sgrid(BB / 16, 2);
    scan_mfma_kernel<<<sgrid, 192, 0, stream>>>(xp, whh_f, bhh_f, whh_b, bhh_b, out);
}

// Round 3
// 988.090 us; speedup vs baseline: 2.7983x; 1.1319x over previous
//
#include <hip/hip_runtime.h>
#include <hip/hip_fp16.h>

// Bidirectional GRU: T=512, B=512, I=100, H=96, gate order (r,z,n).
// proj_mfma_kernel: xp[dir][m][g] = x_row . W_ih[g] + b_ih[g] via f16 MFMA (unchanged).
// scan_mfma_kernel (v2): recurrent matmul via MFMA, swapped operands.
//   6 waves/block (wave w owns 16 hidden cols, all 3 gate classes) -> 2 waves
//   on 2 of 4 SIMDs for latency hiding. h stored f16-only in LDS (recurrence
//   state stays exact fp32 in registers); W_hh kept hi+lo f16 split in VGPRs:
//   hp = Whi.h + Wlo.h (2 MFMA terms, was 3).

#define TT 512
#define BB 512
#define II 100
#define HH 96
#define GG 288   // 3*H
#define SH 104   // LDS h row stride in halves (208B: even b128 bank-group spread)

typedef _Float16 half8 __attribute__((ext_vector_type(8)));
typedef _Float16 half4 __attribute__((ext_vector_type(4)));
typedef float floatx4 __attribute__((ext_vector_type(4)));

__device__ __forceinline__ float fast_rcp(float x) { return __builtin_amdgcn_rcpf(x); }
__device__ __forceinline__ float sigmoidf_(float x) { return fast_rcp(1.f + __expf(-x)); }
__device__ __forceinline__ float tanhf_(float x) {
    float e = __expf(-2.f * x);
    return (1.f - e) * fast_rcp(1.f + e);
}

// ---------------- input projection (MFMA) ----------------
// grid: (TT, 2) — block bx handles the 512 rows of time-step t=bx for dir=by.
// block: 192 threads = 3 waves; wave w owns gates [w*96, w*96+96).
__global__ __launch_bounds__(192) void proj_mfma_kernel(
    const float* __restrict__ x,
    const float* __restrict__ wih_f, const float* __restrict__ bih_f,
    const float* __restrict__ wih_b, const float* __restrict__ bih_b,
    __half* __restrict__ xp)
{
    const int dir = blockIdx.y;
    const int t   = blockIdx.x;
    const int tid = threadIdx.x;
    const int w   = tid >> 6;      // wave 0..2
    const int l   = tid & 63;
    const int l15 = l & 15;
    const int kg  = l >> 4;        // 0..3 (k-group)
    const int n0  = w * 96;

    const float* w_ih = dir ? wih_b : wih_f;
    const float* b_ih = dir ? bih_b : bih_f;

    half8 Bf[6][4];
    float bias[6];
#pragma unroll
    for (int nt = 0; nt < 6; ++nt) {
        const int g = n0 + nt * 16 + l15;
        bias[nt] = b_ih[g];
        const float* wr = w_ih + (size_t)g * II;
#pragma unroll
        for (int kc = 0; kc < 4; ++kc) {
            half8 f;
#pragma unroll
            for (int j = 0; j < 8; ++j) f[j] = (_Float16)0.f;
            if (kc < 3) {
                const int kb = kc * 32 + kg * 8;   // <= 88, +7 = 95 < 100: valid
                const float4* p = (const float4*)(wr + kb);
                float4 a = p[0], b = p[1];
                f[0] = (_Float16)a.x; f[1] = (_Float16)a.y;
                f[2] = (_Float16)a.z; f[3] = (_Float16)a.w;
                f[4] = (_Float16)b.x; f[5] = (_Float16)b.y;
                f[6] = (_Float16)b.z; f[7] = (_Float16)b.w;
            } else if (kg == 0) {
                const float4* p = (const float4*)(wr + 96);  // k = 96..99
                float4 a = p[0];
                f[0] = (_Float16)a.x; f[1] = (_Float16)a.y;
                f[2] = (_Float16)a.z; f[3] = (_Float16)a.w;
            }
            Bf[nt][kc] = f;
        }
    }

    __shared__ __half xs[32][136];
    for (int i = tid; i < 32 * 28; i += 192) {
        const int row = i / 28, c = i - row * 28;
        xs[row][100 + c] = __float2half(0.f);
    }

    __half* out = xp + (size_t)dir * (size_t)(TT * BB) * GG;
    const size_t orow_base = dir ? (size_t)(TT - 1 - t) * BB : (size_t)t * BB;

    for (int s = 0; s < 16; ++s) {
        const int r0 = s * 32;
        __syncthreads();
        const float2* src = (const float2*)(x + ((size_t)t * BB + r0) * II);
        for (int i = tid; i < 1600; i += 192) {
            float2 v = src[i];
            const int row = i / 50, c2 = i - row * 50;
            *(__half2*)&xs[row][2 * c2] = __floats2half2_rn(v.x, v.y);
        }
        __syncthreads();

        floatx4 acc[2][6];
#pragma unroll
        for (int mt = 0; mt < 2; ++mt)
#pragma unroll
            for (int nt = 0; nt < 6; ++nt) {
                acc[mt][nt][0] = bias[nt]; acc[mt][nt][1] = bias[nt];
                acc[mt][nt][2] = bias[nt]; acc[mt][nt][3] = bias[nt];
            }

#pragma unroll
        for (int mt = 0; mt < 2; ++mt) {
            half8 Af[4];
            const char* abase = (const char*)&xs[0][0] + (mt * 16 + l15) * 272 + kg * 16;
#pragma unroll
            for (int kc = 0; kc < 4; ++kc)
                Af[kc] = *(const half8*)(abase + kc * 64);
#pragma unroll
            for (int nt = 0; nt < 6; ++nt)
#pragma unroll
                for (int kc = 0; kc < 4; ++kc)
                    acc[mt][nt] = __builtin_amdgcn_mfma_f32_16x16x32_f16(
                        Af[kc], Bf[nt][kc], acc[mt][nt], 0, 0, 0);
        }

#pragma unroll
        for (int mt = 0; mt < 2; ++mt) {
#pragma unroll
            for (int nt = 0; nt < 6; ++nt) {
                const int g = n0 + nt * 16 + l15;
#pragma unroll
                for (int i = 0; i < 4; ++i) {
                    const int b = r0 + mt * 16 + kg * 4 + i;
                    out[(orow_base + b) * GG + g] = __float2half(acc[mt][nt][i]);
                }
            }
        }
    }
}

// ---------------- recurrent scan (MFMA, 6-wave) ----------------
// grid: (BB/16, 2), block: 384 = 6 waves. Block owns 16 batch rows (r0..r0+15).
// Wave w owns hidden cols j in [16w, 16w+16) for ALL 3 classes (r,z,n tiles).
// Lane (l15,kg): C element = (col-local kg*4+i, row l15); r/z/n colocated.
__global__ __launch_bounds__(384, 1) void scan_mfma_kernel(
    const __half* __restrict__ xp,
    const float* __restrict__ whh_f, const float* __restrict__ bhh_f,
    const float* __restrict__ whh_b, const float* __restrict__ bhh_b,
    float* __restrict__ out)
{
    const int dir = blockIdx.y;
    const int r0  = blockIdx.x * 16;
    const int tid = threadIdx.x;
    const int w   = tid >> 6;      // 0..5
    const int l   = tid & 63;
    const int l15 = l & 15;
    const int kg  = l >> 4;

    const float* whh = dir ? whh_b : whh_f;
    const float* bhh = dir ? bhh_b : bhh_f;

    // A-fragments (W_hh) hi/lo split; cls tile: gates cls*96 + 16w + [0,16)
    half8 Whi[3][3], Wlo[3][3];
    floatx4 bias[3];
#pragma unroll
    for (int cls = 0; cls < 3; ++cls) {
        const int g = cls * 96 + 16 * w + l15;
        const float* wr = whh + (size_t)g * HH;
#pragma unroll
        for (int kc = 0; kc < 3; ++kc) {
            const float4* p = (const float4*)(wr + kc * 32 + kg * 8);
            float4 a = p[0], b = p[1];
            half8 hi, lo;
            float v[8] = {a.x, a.y, a.z, a.w, b.x, b.y, b.z, b.w};
#pragma unroll
            for (int j = 0; j < 8; ++j) {
                _Float16 h = (_Float16)v[j];
                hi[j] = h;
                lo[j] = (_Float16)(v[j] - (float)h);
            }
            Whi[cls][kc] = hi;
            Wlo[cls][kc] = lo;
        }
        const int gb = cls * 96 + 16 * w + kg * 4;
        bias[cls][0] = bhh[gb + 0]; bias[cls][1] = bhh[gb + 1];
        bias[cls][2] = bhh[gb + 2]; bias[cls][3] = bhh[gb + 3];
    }

    // h state: f16 only, double-buffered, padded stride (even bank-group spread)
    __shared__ __align__(16) _Float16 hS[2][16][SH];
    for (int i = tid; i < 2 * 16 * SH / 2; i += 384)
        ((unsigned*)hS)[i] = 0u;

    float hold[4];  // exact fp32 recurrence state: h[row l15][col 16w+4kg+i]
#pragma unroll
    for (int i = 0; i < 4; ++i) hold[i] = 0.f;

    const __half* xpd  = xp + (size_t)dir * (size_t)(TT * BB) * GG;
    const __half* xptr = xpd + ((size_t)(r0 + l15)) * GG + 16 * w + 4 * kg;
    const size_t  xstep = (size_t)BB * GG;  // halves per time step

    half4 xc[3], xn[3];
#pragma unroll
    for (int cls = 0; cls < 3; ++cls)
        xc[cls] = *(const half4*)(xptr + cls * 96);
    const __half* xq = xptr + xstep;  // prefetch pointer (t+1)

    float* optr = out + ((size_t)(dir ? TT - 1 : 0) * BB + r0 + l15) * (2 * HH)
                      + dir * HH + 16 * w + 4 * kg;
    const ptrdiff_t ostep = (dir ? -(ptrdiff_t)1 : (ptrdiff_t)1) * (ptrdiff_t)(BB * 2 * HH);

    __syncthreads();

    for (int t = 0; t < TT; ++t) {
        // prefetch next step's xp early (hidden under MFMA+gates)
        if (t + 1 < TT) {
#pragma unroll
            for (int cls = 0; cls < 3; ++cls)
                xn[cls] = *(const half4*)(xq + cls * 96);
        }

        const int cur = t & 1, nxt = cur ^ 1;

        // B-fragments: h^T, lane col=l15(=batch row), k = kc*32+kg*8+j
        half8 hb[3];
#pragma unroll
        for (int kc = 0; kc < 3; ++kc)
            hb[kc] = *(const half8*)&hS[cur][l15][kc * 32 + kg * 8];

        floatx4 acc[3];
#pragma unroll
        for (int cls = 0; cls < 3; ++cls) {
            acc[cls] = bias[cls];
#pragma unroll
            for (int kc = 0; kc < 3; ++kc) {
                acc[cls] = __builtin_amdgcn_mfma_f32_16x16x32_f16(Whi[cls][kc], hb[kc], acc[cls], 0, 0, 0);
                acc[cls] = __builtin_amdgcn_mfma_f32_16x16x32_f16(Wlo[cls][kc], hb[kc], acc[cls], 0, 0, 0);
            }
        }

        float4 o;
        half4 nh;
#pragma unroll
        for (int i = 0; i < 4; ++i) {
            const float r = sigmoidf_((float)xc[0][i] + acc[0][i]);
            const float z = sigmoidf_((float)xc[1][i] + acc[1][i]);
            const float n = tanhf_((float)xc[2][i] + r * acc[2][i]);
            const float hv = z * (hold[i] - n) + n;
            hold[i] = hv;
            ((float*)&o)[i] = hv;
            nh[i] = (_Float16)hv;
        }
        *(float4*)optr = o;
        *(half4*)&hS[nxt][l15][16 * w + 4 * kg] = nh;

        __syncthreads();  // h[nxt] complete before next step reads it
        optr += ostep;
        xq += xstep;
#pragma unroll
        for (int i = 0; i < 3; ++i) xc[i] = xn[i];
    }
}

__global__ void sentinel_kernel(float* out) {
    if (threadIdx.x == 0 && blockIdx.x == 0) out[0] = 1e9f;  // ws too small marker
}

extern "C" void kernel_launch(void* const* d_in, const int* in_sizes, int n_in,
                              void* d_out, int out_size, void* d_ws, size_t ws_size,
                              hipStream_t stream)
{
    const float* x     = (const float*)d_in[0];
    const float* wih_f = (const float*)d_in[1];
    const float* whh_f = (const float*)d_in[2];
    const float* bih_f = (const float*)d_in[3];
    const float* bhh_f = (const float*)d_in[4];
    const float* wih_b = (const float*)d_in[5];
    const float* whh_b = (const float*)d_in[6];
    const float* bih_b = (const float*)d_in[7];
    const float* bhh_b = (const float*)d_in[8];
    float* out = (float*)d_out;

    const size_t ws_needed = (size_t)2 * TT * BB * GG * sizeof(__half);  // ~302 MB
    if (ws_size < ws_needed) {
        sentinel_kernel<<<1, 64, 0, stream>>>(out);
        return;
    }
    __half* xp = (__half*)d_ws;

    dim3 pgrid(TT, 2);
    proj_mfma_kernel<<<pgrid, 192, 0, stream>>>(x, wih_f, bih_f, wih_b, bih_b, xp);

    dim3 sgrid(BB / 16, 2);
    scan_mfma_kernel<<<sgrid, 384, 0, stream>>>(xp, whh_f, bhh_f, whh_b, bhh_b, out);
}